// Round 1
// baseline (108.726 us; speedup 1.0000x reference)
//
#include <hip/hip_runtime.h>

#define IN_F 4096
#define OUT_F 11008
#define M 8
#define KROWS 512                     // IN_F / 8 packed rows of qweight
#define KSLICES 16
#define ROWS_PER_SLICE (KROWS / KSLICES)   // 32 packed rows = 256 K-values per slice

// Write bias into out (d_out is poisoned 0xAA before every launch).
__global__ __launch_bounds__(256) void init_out_kernel(
    const float* __restrict__ bias, float* __restrict__ out)
{
    int idx = blockIdx.x * 256 + threadIdx.x;
    if (idx < M * OUT_F) {
        out[idx] = bias[idx % OUT_F];   // out is (M, OUT_F) row-major
    }
}

__global__ __launch_bounds__(256) void gptq_gemm_kernel(
    const float* __restrict__ x,      // (M, IN_F)
    const int*   __restrict__ qw,     // (KROWS, OUT_F)
    const int*   __restrict__ qz,     // (1, OUT_F/8)
    const float* __restrict__ sc,     // (1, OUT_F)
    float*       __restrict__ out)    // (M, OUT_F)
{
    const int j = blockIdx.x * 256 + threadIdx.x;   // output column
    if (j >= OUT_F) return;
    const int i0 = blockIdx.y * ROWS_PER_SLICE;     // first packed row of this K-slice

    // GPTQ zero point for this column: ((qz >> 4*(j%8)) & 15) + 1
    const int   zq = qz[j >> 3];
    const float zf = (float)(((zq >> ((j & 7) * 4)) & 15) + 1);
    const float s  = sc[j];

    float acc[M];
#pragma unroll
    for (int r = 0; r < M; ++r) acc[r] = 0.0f;

    // Inner loop: per int32 of qweight -> 8 weights -> 8 rows each.
    // x[] indices are wave-uniform -> compiler scalarizes to s_load (SMEM),
    // keeping VALU for bfe/cvt/fma only.
#pragma unroll 2
    for (int i = 0; i < ROWS_PER_SLICE; ++i) {
        const int q     = qw[(size_t)(i0 + i) * OUT_F + j];   // coalesced
        const int kbase = (i0 + i) * 8;
#pragma unroll
        for (int p = 0; p < 8; ++p) {
            const float wf = (float)((q >> (p * 4)) & 15) - zf;
#pragma unroll
            for (int r = 0; r < M; ++r) {
                acc[r] = fmaf(wf, x[r * IN_F + kbase + p], acc[r]);
            }
        }
    }

#pragma unroll
    for (int r = 0; r < M; ++r) {
        atomicAdd(&out[r * OUT_F + j], s * acc[r]);
    }
}

extern "C" void kernel_launch(void* const* d_in, const int* in_sizes, int n_in,
                              void* d_out, int out_size, void* d_ws, size_t ws_size,
                              hipStream_t stream) {
    const float* x    = (const float*)d_in[0];
    const int*   qw   = (const int*)d_in[1];
    const int*   qz   = (const int*)d_in[2];
    const float* sc   = (const float*)d_in[3];
    const float* bias = (const float*)d_in[4];
    float* out = (float*)d_out;

    // 1) out = bias (broadcast over rows)
    int init_blocks = (M * OUT_F + 255) / 256;
    hipLaunchKernelGGL(init_out_kernel, dim3(init_blocks), dim3(256), 0, stream,
                       bias, out);

    // 2) K-sliced dequant-GEMM, atomic accumulate
    dim3 grid(OUT_F / 256, KSLICES);   // 43 x 16 = 688 blocks
    hipLaunchKernelGGL(gptq_gemm_kernel, grid, dim3(256), 0, stream,
                       x, qw, qz, sc, out);
}

// Round 2
// 96.618 us; speedup vs baseline: 1.1253x; 1.1253x over previous
//
#include <hip/hip_runtime.h>

#define IN_F 4096
#define OUT_F 11008
#define M 8
#define KROWS 512                         // IN_F/8 packed qweight rows
#define S_SLICES 32
#define ROWS_PER_SLICE (KROWS / S_SLICES) // 16 packed rows = 128 k-values
#define GEMM_THREADS 128                  // 2 waves; block covers 256 columns
#define NJ4 (OUT_F / 4)                   // 2752

// ---------------- rowsum[r] = sum_k x[r][k] ----------------
__global__ __launch_bounds__(64) void rowsum_kernel(
    const float* __restrict__ x, float* __restrict__ rs)
{
    const int r = blockIdx.x;       // 0..7
    const int t = threadIdx.x;      // 0..63
    const float4* xp = (const float4*)(x + (size_t)r * IN_F);
    float s = 0.0f;
#pragma unroll
    for (int c = 0; c < 16; ++c) {  // 16*64 = 1024 float4 = 4096 floats
        float4 v = xp[c * 64 + t];
        s += v.x + v.y + v.z + v.w;
    }
#pragma unroll
    for (int off = 1; off < 64; off <<= 1) s += __shfl_xor(s, off, 64);
    if (t == 0) rs[r] = s;
}

// ---------------- partial GEMM: P[slice][r][j] = sum_{k in slice} w[k][j]*x[r][k] ----------------
__global__ __launch_bounds__(GEMM_THREADS) void gptq_gemm_partial(
    const float* __restrict__ x,    // (M, IN_F)
    const int*   __restrict__ qw,   // (KROWS, OUT_F)
    float*       __restrict__ P)    // (S_SLICES, M, OUT_F)
{
    const int t  = threadIdx.x;
    const int j0 = blockIdx.x * (GEMM_THREADS * 2) + 2 * t;  // 2 cols/thread
    const int i0 = blockIdx.y * ROWS_PER_SLICE;

    float acc[M][2];
#pragma unroll
    for (int r = 0; r < M; ++r) { acc[r][0] = 0.0f; acc[r][1] = 0.0f; }

    for (int i = 0; i < ROWS_PER_SLICE; ++i) {
        const int row = i0 + i;
        const int2 q = *(const int2*)(qw + (size_t)row * OUT_F + j0); // coalesced 8B/lane
        const int kb = row * 8;

        // x[r][kb..kb+7] for all 8 rows: wave-uniform float4 loads (L1 broadcast)
        float4 xa[M], xb[M];
#pragma unroll
        for (int r = 0; r < M; ++r) {
            const float* xp = x + (size_t)r * IN_F + kb;
            xa[r] = *(const float4*)xp;
            xb[r] = *(const float4*)(xp + 4);
        }

#pragma unroll
        for (int p = 0; p < 8; ++p) {
            const float w0 = (float)((q.x >> (4 * p)) & 15);   // bfe + cvt
            const float w1 = (float)((q.y >> (4 * p)) & 15);
#pragma unroll
            for (int r = 0; r < M; ++r) {
                const float xv = (p < 4) ? ((const float*)&xa[r])[p]
                                         : ((const float*)&xb[r])[p - 4];
                acc[r][0] = fmaf(w0, xv, acc[r][0]);
                acc[r][1] = fmaf(w1, xv, acc[r][1]);
            }
        }
    }

    float* Pp = P + (size_t)blockIdx.y * M * OUT_F;
#pragma unroll
    for (int r = 0; r < M; ++r) {
        float2 v; v.x = acc[r][0]; v.y = acc[r][1];
        *(float2*)(Pp + (size_t)r * OUT_F + j0) = v;           // coalesced 8B/lane
    }
}

// ---------------- reduce: out[r][j] = bias[j] + s_j*(sum_s P[s][r][j] - z_j*rowsum[r]) ----------------
__global__ __launch_bounds__(256) void reduce_kernel(
    const float* __restrict__ P,
    const float* __restrict__ rs,
    const int*   __restrict__ qz,   // (1, OUT_F/8)
    const float* __restrict__ sc,   // (1, OUT_F)
    const float* __restrict__ bias, // (OUT_F)
    float*       __restrict__ out)  // (M, OUT_F)
{
    const int idx = blockIdx.x * 256 + threadIdx.x;  // 0..22015
    const int jq  = idx % NJ4;
    const int r   = idx / NJ4;
    const int j0  = jq * 4;

    float4 acc = {0.0f, 0.0f, 0.0f, 0.0f};
#pragma unroll 8
    for (int s = 0; s < S_SLICES; ++s) {
        const float4 v = *(const float4*)(P + (size_t)s * M * OUT_F + (size_t)r * OUT_F + j0);
        acc.x += v.x; acc.y += v.y; acc.z += v.z; acc.w += v.w;
    }

    const int zw = qz[j0 >> 3];
    const int sh = (j0 & 7) * 4;                     // 0 or 16
    const float z0 = (float)(((zw >> (sh     )) & 15) + 1);
    const float z1 = (float)(((zw >> (sh +  4)) & 15) + 1);
    const float z2 = (float)(((zw >> (sh +  8)) & 15) + 1);
    const float z3 = (float)(((zw >> (sh + 12)) & 15) + 1);

    const float rsum = rs[r];
    const float4 s4 = *(const float4*)(sc + j0);
    const float4 b4 = *(const float4*)(bias + j0);

    float4 o;
    o.x = fmaf(s4.x, acc.x - z0 * rsum, b4.x);
    o.y = fmaf(s4.y, acc.y - z1 * rsum, b4.y);
    o.z = fmaf(s4.z, acc.z - z2 * rsum, b4.z);
    o.w = fmaf(s4.w, acc.w - z3 * rsum, b4.w);
    *(float4*)(out + (size_t)r * OUT_F + j0) = o;
}

extern "C" void kernel_launch(void* const* d_in, const int* in_sizes, int n_in,
                              void* d_out, int out_size, void* d_ws, size_t ws_size,
                              hipStream_t stream) {
    const float* x    = (const float*)d_in[0];
    const int*   qw   = (const int*)d_in[1];
    const int*   qz   = (const int*)d_in[2];
    const float* sc   = (const float*)d_in[3];
    const float* bias = (const float*)d_in[4];
    float* out = (float*)d_out;

    float* P  = (float*)d_ws;                                  // S_SLICES*M*OUT_F floats
    float* rs = P + (size_t)S_SLICES * M * OUT_F;              // 8 floats

    hipLaunchKernelGGL(rowsum_kernel, dim3(M), dim3(64), 0, stream, x, rs);

    dim3 grid(OUT_F / (GEMM_THREADS * 2), S_SLICES);           // 43 x 32
    hipLaunchKernelGGL(gptq_gemm_partial, grid, dim3(GEMM_THREADS), 0, stream,
                       x, qw, P);

    hipLaunchKernelGGL(reduce_kernel, dim3((M * NJ4) / 256), dim3(256), 0, stream,
                       P, rs, qz, sc, bias, out);
}

// Round 3
// 93.596 us; speedup vs baseline: 1.1616x; 1.0323x over previous
//
#include <hip/hip_runtime.h>

#define IN_F 4096
#define OUT_F 11008
#define M 8
#define KROWS 512                         // IN_F/8 packed qweight rows
#define S_SLICES 64
#define RPS (KROWS / S_SLICES)            // 8 packed rows = 64 k-values per slice
#define GEMM_THREADS 128                  // covers 256 columns (2 cols/thread)

// ---------------- rowsum[r] = sum_k x[r][k] ----------------
__global__ __launch_bounds__(64) void rowsum_kernel(
    const float* __restrict__ x, float* __restrict__ rs)
{
    const int r = blockIdx.x;       // 0..7
    const int t = threadIdx.x;      // 0..63
    const float4* xp = (const float4*)(x + (size_t)r * IN_F);
    float s = 0.0f;
#pragma unroll
    for (int c = 0; c < 16; ++c) {  // 16*64 = 1024 float4 = 4096 floats
        float4 v = xp[c * 64 + t];
        s += v.x + v.y + v.z + v.w;
    }
#pragma unroll
    for (int off = 1; off < 64; off <<= 1) s += __shfl_xor(s, off, 64);
    if (t == 0) rs[r] = s;
}

// ---------------- partial GEMM: P[slice][r][j] = sum_{k in slice} w[k][j]*x[r][k] ----------------
__global__ __launch_bounds__(GEMM_THREADS) void gptq_gemm_partial(
    const float* __restrict__ x,    // (M, IN_F)
    const int*   __restrict__ qw,   // (KROWS, OUT_F)
    float*       __restrict__ P)    // (S_SLICES, M, OUT_F)
{
    const int t  = threadIdx.x;
    const int j0 = blockIdx.x * (GEMM_THREADS * 2) + 2 * t;  // 2 cols/thread
    const int i0 = blockIdx.y * RPS;

    float2 acc[M];
#pragma unroll
    for (int r = 0; r < M; ++r) { acc[r].x = 0.0f; acc[r].y = 0.0f; }

    const int* qp = qw + (size_t)i0 * OUT_F + j0;
    int2 q = *(const int2*)qp;                        // prefetch row 0

#pragma unroll
    for (int i = 0; i < RPS; ++i) {
        int2 qn = q;
        if (i + 1 < RPS)
            qn = *(const int2*)(qp + (size_t)(i + 1) * OUT_F);  // prefetch next row
        const int kb = (i0 + i) * 8;

        // process the 8 nibbles in two halves to keep x-register pressure low
#pragma unroll
        for (int h = 0; h < 2; ++h) {
            float4 xv[M];
#pragma unroll
            for (int r = 0; r < M; ++r)
                xv[r] = *(const float4*)(x + (size_t)r * IN_F + kb + 4 * h);
#pragma unroll
            for (int p = 0; p < 4; ++p) {
                const int sh = 4 * (4 * h + p);
                const float w0 = (float)((q.x >> sh) & 15);
                const float w1 = (float)((q.y >> sh) & 15);
#pragma unroll
                for (int r = 0; r < M; ++r) {
                    const float xs = ((const float*)&xv[r])[p];
                    acc[r].x = fmaf(w0, xs, acc[r].x);
                    acc[r].y = fmaf(w1, xs, acc[r].y);
                }
            }
        }
        q = qn;
    }

    float* Pp = P + (size_t)blockIdx.y * M * OUT_F;
#pragma unroll
    for (int r = 0; r < M; ++r)
        *(float2*)(Pp + (size_t)r * OUT_F + j0) = acc[r];    // coalesced 8B/lane
}

// ---------------- reduce: out[r][j] = bias[j] + s_j*(sum_s P[s][r][j] - z_j*rowsum[r]) ----------------
__global__ __launch_bounds__(256) void reduce_kernel(
    const float* __restrict__ P,
    const float* __restrict__ rs,
    const int*   __restrict__ qz,   // (1, OUT_F/8)
    const float* __restrict__ sc,   // (1, OUT_F)
    const float* __restrict__ bias, // (OUT_F)
    float*       __restrict__ out)  // (M, OUT_F)
{
    const int idx = blockIdx.x * 256 + threadIdx.x;  // 0 .. M*OUT_F-1 (88064)
    const int j = idx % OUT_F;                        // consecutive lanes -> consecutive j
    const int r = idx / OUT_F;

    float acc = 0.0f;
#pragma unroll 16
    for (int s = 0; s < S_SLICES; ++s)
        acc += P[(size_t)s * M * OUT_F + (size_t)r * OUT_F + j];

    const int zw = qz[j >> 3];
    const float z = (float)(((zw >> ((j & 7) * 4)) & 15) + 1);

    out[(size_t)r * OUT_F + j] = fmaf(sc[j], acc - z * rs[r], bias[j]);
}

extern "C" void kernel_launch(void* const* d_in, const int* in_sizes, int n_in,
                              void* d_out, int out_size, void* d_ws, size_t ws_size,
                              hipStream_t stream) {
    const float* x    = (const float*)d_in[0];
    const int*   qw   = (const int*)d_in[1];
    const int*   qz   = (const int*)d_in[2];
    const float* sc   = (const float*)d_in[3];
    const float* bias = (const float*)d_in[4];
    float* out = (float*)d_out;

    float* P  = (float*)d_ws;                                  // S_SLICES*M*OUT_F floats (22.5 MB)
    float* rs = P + (size_t)S_SLICES * M * OUT_F;              // 8 floats

    hipLaunchKernelGGL(rowsum_kernel, dim3(M), dim3(64), 0, stream, x, rs);

    dim3 grid(OUT_F / (GEMM_THREADS * 2), S_SLICES);           // 43 x 64 = 2752 blocks
    hipLaunchKernelGGL(gptq_gemm_partial, grid, dim3(GEMM_THREADS), 0, stream,
                       x, qw, P);

    hipLaunchKernelGGL(reduce_kernel, dim3((M * OUT_F) / 256), dim3(256), 0, stream,
                       P, rs, qz, sc, bias, out);
}

// Round 4
// 90.347 us; speedup vs baseline: 1.2034x; 1.0360x over previous
//
#include <hip/hip_runtime.h>

#define IN_F 4096
#define OUT_F 11008
#define M 8
#define S_SLICES 16
#define KPS (IN_F / S_SLICES)     // 256 k-values per slice
#define RPSL (KPS / 8)            // 32 packed qweight rows per slice
#define STEPS (KPS / 32)          // 8 MFMA K-steps per slice

typedef __bf16 bf16x8 __attribute__((ext_vector_type(8)));
typedef float  f32x4  __attribute__((ext_vector_type(4)));
typedef unsigned short us8 __attribute__((ext_vector_type(8)));

// bf16 truncation of fp32 (exact for small ints; consistent across kernels)
__device__ __forceinline__ float trunc_bf(float v) {
    return __uint_as_float(__float_as_uint(v) & 0xffff0000u);
}

// ---------------- rowsum[r] = sum_k truncbf(x[r][k]) ----------------
__global__ __launch_bounds__(64) void rowsum_kernel(
    const float* __restrict__ x, float* __restrict__ rs)
{
    const int r = blockIdx.x, t = threadIdx.x;
    const float4* xp = (const float4*)(x + (size_t)r * IN_F);
    float s = 0.0f;
#pragma unroll
    for (int c = 0; c < 16; ++c) {
        float4 v = xp[c * 64 + t];
        s += trunc_bf(v.x) + trunc_bf(v.y) + trunc_bf(v.z) + trunc_bf(v.w);
    }
#pragma unroll
    for (int off = 1; off < 64; off <<= 1) s += __shfl_xor(s, off, 64);
    if (t == 0) rs[r] = s;
}

// ---------------- x fp32 -> bf16 bits, rows 8..15 zeroed (MFMA A pad) ----------------
__global__ __launch_bounds__(256) void convert_x_kernel(
    const float* __restrict__ x, unsigned short* __restrict__ xb) // (16, IN_F)
{
    const int idx = blockIdx.x * 256 + threadIdx.x;  // 0..8191, 8 elems each
    const int r = idx >> 9;                          // IN_F/8 = 512 chunks/row
    const int c = (idx & 511) * 8;
    us8 o;
    if (r < M) {
        const float4 v0 = *(const float4*)(x + (size_t)r * IN_F + c);
        const float4 v1 = *(const float4*)(x + (size_t)r * IN_F + c + 4);
        o[0] = (unsigned short)(__float_as_uint(v0.x) >> 16);
        o[1] = (unsigned short)(__float_as_uint(v0.y) >> 16);
        o[2] = (unsigned short)(__float_as_uint(v0.z) >> 16);
        o[3] = (unsigned short)(__float_as_uint(v0.w) >> 16);
        o[4] = (unsigned short)(__float_as_uint(v1.x) >> 16);
        o[5] = (unsigned short)(__float_as_uint(v1.y) >> 16);
        o[6] = (unsigned short)(__float_as_uint(v1.z) >> 16);
        o[7] = (unsigned short)(__float_as_uint(v1.w) >> 16);
    } else {
        o = (us8)0;
    }
    *(us8*)(xb + (size_t)r * IN_F + c) = o;
}

// ---------------- MFMA partial GEMM: P[slice][r][col] = sum_{k in slice} w[k][col]*x[r][k] --------
// Layouts (m89/m91-verified): A[m=lane&15][k=quad*8+j]; B[k=quad*8+j][n=lane&15];
// D[row=quad*4+reg][col=lane&15]. B-frag k-run of 8 == nibbles of ONE qweight int32 (LSB-first).
__global__ __launch_bounds__(256) void gptq_mfma_kernel(
    const int* __restrict__ qw,             // (512, OUT_F)
    const unsigned short* __restrict__ xb,  // (16, IN_F) bf16 bits, rows 8..15 = 0
    float* __restrict__ P)                  // (S_SLICES, M, OUT_F)
{
    const int lane = threadIdx.x & 63;
    const int wv   = threadIdx.x >> 6;                 // wave 0..3
    const int t    = lane & 15;                        // = m (A) = n (B) = col (D)
    const int quad = lane >> 4;                        // 0..3
    const int col  = (blockIdx.x * 4 + wv) * 16 + t;   // 172*4*16 = 11008 exact
    const int i0   = blockIdx.y * RPSL;                // first packed row of slice
    const int kb   = blockIdx.y * KPS;                 // first k of slice

    // Issue ALL slice loads up front: 8 qweight (4 B/lane) + 8 A-frags (16 B/lane)
    // = 10 KB/wave in flight; vmcnt in-order drain then hits HBM latency once.
    int    qv [STEPS];
    bf16x8 afr[STEPS];
    const int* qcol = qw + (size_t)(i0 + quad) * OUT_F + col;
    const unsigned short* xrow = xb + (size_t)t * IN_F + kb + quad * 8;
#pragma unroll
    for (int s = 0; s < STEPS; ++s) {
        qv[s]  = qcol[(size_t)s * 4 * OUT_F];              // row i0 + s*4 + quad
        afr[s] = *(const bf16x8*)(xrow + s * 32);          // k = kb + s*32 + quad*8
    }

    f32x4 acc = {0.f, 0.f, 0.f, 0.f};
#pragma unroll
    for (int s = 0; s < STEPS; ++s) {
        union { unsigned short u[8]; bf16x8 v; } bf;
#pragma unroll
        for (int j = 0; j < 8; ++j) {
            const float f = (float)((qv[s] >> (4 * j)) & 15);   // nibble exact in bf16
            bf.u[j] = (unsigned short)(__float_as_uint(f) >> 16);
        }
        acc = __builtin_amdgcn_mfma_f32_16x16x32_bf16(afr[s], bf.v, acc, 0, 0, 0);
    }

    // D rows 0..7 are real x-rows (quads 0,1); rows 8..15 are the zero-pad.
    const int r0 = quad * 4;
    if (r0 < M) {
        float* Pp = P + (size_t)blockIdx.y * (M * OUT_F);
#pragma unroll
        for (int r = 0; r < 4; ++r)
            Pp[(size_t)(r0 + r) * OUT_F + col] = acc[r];
    }
}

// ---------------- out[r][j] = bias[j] + s_j*(sum_s P[s][r][j] - z_j*rowsum[r]) ----------------
__global__ __launch_bounds__(256) void reduce_kernel(
    const float* __restrict__ P, const float* __restrict__ rs,
    const int* __restrict__ qz, const float* __restrict__ sc,
    const float* __restrict__ bias, float* __restrict__ out)
{
    const int idx = blockIdx.x * 256 + threadIdx.x;
    const int j = idx % OUT_F;
    const int r = idx / OUT_F;

    float acc = 0.0f;
#pragma unroll
    for (int s = 0; s < S_SLICES; ++s)
        acc += P[(size_t)s * M * OUT_F + (size_t)r * OUT_F + j];

    const int zw = qz[j >> 3];
    const float z = (float)(((zw >> ((j & 7) * 4)) & 15) + 1);
    out[(size_t)r * OUT_F + j] = fmaf(sc[j], acc - z * rs[r], bias[j]);
}

extern "C" void kernel_launch(void* const* d_in, const int* in_sizes, int n_in,
                              void* d_out, int out_size, void* d_ws, size_t ws_size,
                              hipStream_t stream) {
    const float* x    = (const float*)d_in[0];
    const int*   qw   = (const int*)d_in[1];
    const int*   qz   = (const int*)d_in[2];
    const float* sc   = (const float*)d_in[3];
    const float* bias = (const float*)d_in[4];
    float* out = (float*)d_out;

    float*          P  = (float*)d_ws;                               // 5.6 MB
    unsigned short* xb = (unsigned short*)((char*)d_ws + (8u << 20));// 128 KB
    float*          rs = (float*)((char*)d_ws + (16u << 20));        // 32 B

    hipLaunchKernelGGL(rowsum_kernel, dim3(M), dim3(64), 0, stream, x, rs);
    hipLaunchKernelGGL(convert_x_kernel, dim3(32), dim3(256), 0, stream, x, xb);
    hipLaunchKernelGGL(gptq_mfma_kernel, dim3(OUT_F / 64, S_SLICES), dim3(256), 0, stream,
                       qw, xb, P);
    hipLaunchKernelGGL(reduce_kernel, dim3((M * OUT_F) / 256), dim3(256), 0, stream,
                       P, rs, qz, sc, bias, out);
}